// Round 16
// baseline (430.799 us; speedup 1.0000x reference)
//
#include <hip/hip_runtime.h>
#include <hip/hip_bf16.h>
#include <cstdint>

#define DI __device__ __forceinline__

typedef __attribute__((ext_vector_type(4))) float f32x4;
typedef __attribute__((ext_vector_type(8))) short bf16x8;

static constexpr int B_ = 16384, I_ = 1024, H_ = 1024;
static constexpr int M = B_;          // 16384 rows
static constexpr int N = 4 * H_;      // 4096 gate-cols (permuted)
static constexpr int K = I_ + H_;     // 2048 ([x | h])
static constexpr int NT = K / 64;     // 32 K-tiles

// workspace layout (bytes)
static constexpr size_t OFF_A  = 0;                         // A2 frag-layout (64 MB)
static constexpr size_t OFF_W  = OFF_A + (size_t)M * K * 2; // W2 frag-layout (16 MB)
static constexpr size_t OFF_BI = OFF_W + (size_t)N * K * 2; // N f32      (16 KB)

DI unsigned short f2bf(float f) {
    union { float f; unsigned u; } v; v.f = f;
    unsigned r = v.u + 0x7FFFu + ((v.u >> 16) & 1u);
    return (unsigned short)(r >> 16);
}

// ---------------------------------------------------------------- convert A2
// A2 = [x|h] in MFMA A-fragment layout. Chunk (mf, s) is 1 KB: lane l holds
// A'[mf*16 + (l&15)][s*32 + (l>>4)*8 .. +7]. A wave's A-frag load is 64
// lanes x 16B contiguous. Lanes {l, l+16, l+32, l+48} together consume one
// full 128B source line, so reads are line-coalesced.
__global__ void cvt_a2(const float* __restrict__ x, const float* __restrict__ h,
                       unsigned short* __restrict__ A2)
{
    int tid  = blockIdx.x * blockDim.x + threadIdx.x;   // 4,194,304 threads
    int lane = tid & 63;
    int s    = (tid >> 6) & 63;
    int mf   = tid >> 12;               // 0..1023
    int row  = (mf << 4) | (lane & 15);
    int k0   = (s << 5) + ((lane >> 4) << 3);   // multiple of 8

    const float* p = (k0 < I_) ? x + (size_t)row * I_ + k0
                               : h + (size_t)row * H_ + (k0 - I_);
    float4 v0 = *(const float4*)p;
    float4 v1 = *(const float4*)(p + 4);
    unsigned short o[8] = { f2bf(v0.x), f2bf(v0.y), f2bf(v0.z), f2bf(v0.w),
                            f2bf(v1.x), f2bf(v1.y), f2bf(v1.z), f2bf(v1.w) };
    unsigned short* d = A2 + (((size_t)mf * 64 + s) << 9) + (lane << 3);
    *(ushort4*)d       = *(ushort4*)&o[0];
    *(ushort4*)(d + 4) = *(ushort4*)&o[4];
}

// ---------------------------------------------------------------- convert W2
// W2 = weights in MFMA B-fragment layout, gate-permuted column space
// (GEMM col c = g64*64 + gate*16 + hcol16). Chunk (f, s) as in A2.
__global__ void cvt_w2(const float* __restrict__ Wx, const float* __restrict__ Wh,
                       unsigned short* __restrict__ W2)
{
    int tid  = blockIdx.x * blockDim.x + threadIdx.x;   // 1,048,576 threads
    int lane = tid & 63;
    int s    = (tid >> 6) & 63;
    int f    = tid >> 12;               // 0..255
    int col16 = lane & 15;
    int gate  = f & 3;
    int hcol  = ((f >> 2) << 4) | col16;
    int srow  = gate * H_ + hcol;       // row in the [4,H] weight stack
    int k0    = (s << 5) + ((lane >> 4) << 3);

    const float* p = (k0 < I_) ? Wx + (size_t)srow * I_ + k0
                               : Wh + (size_t)srow * H_ + (k0 - I_);
    float4 v0 = *(const float4*)p;
    float4 v1 = *(const float4*)(p + 4);
    unsigned short o[8] = { f2bf(v0.x), f2bf(v0.y), f2bf(v0.z), f2bf(v0.w),
                            f2bf(v1.x), f2bf(v1.y), f2bf(v1.z), f2bf(v1.w) };
    unsigned short* d = W2 + (((size_t)f * 64 + s) << 9) + (lane << 3);
    *(ushort4*)d       = *(ushort4*)&o[0];
    *(ushort4*)(d + 4) = *(ushort4*)&o[4];
}

__global__ void bias_kernel(const float* __restrict__ bx, const float* __restrict__ bh,
                            float* __restrict__ bias)
{
    int r = blockIdx.x * blockDim.x + threadIdx.x;
    if (r < N) {
        int gate = (r >> 4) & 3;
        int hcol = ((r >> 6) << 4) | (r & 15);
        int s = gate * H_ + hcol;
        bias[r] = bx[s] + bh[s];
    }
}

// ---------------------------------------------------------------- GEMM 256x256
// ZERO-LDS, ZERO-BARRIER streaming GEMM. Both operands live in global
// fragment-layout buffers (A2: L3-resident 64MB; W2: 2MB/XCD L2-resident via
// the partitioned mapping). Per wave per K-tile: 24 coalesced 1KB VMEM loads
// + 64 MFMAs. No barriers anywhere -> waves free-run and the compiler can
// software-pipeline next-tile loads under current-tile MFMAs (impossible in
// every LDS/barrier variant, which all serialized at ~5600 cy/tile).
DI float sigf(float v) { return 1.f / (1.f + __expf(-v)); }
DI float tanhfast(float v) {
    float vc = fminf(fmaxf(v, -15.f), 15.f);
    float e  = __expf(2.f * vc);
    return (e - 1.f) / (e + 1.f);
}

__global__ __launch_bounds__(512, 2) void gemm_lstm(
    const unsigned short* __restrict__ A2, const unsigned short* __restrict__ W2,
    const float* __restrict__ bias, const float* __restrict__ c,
    float* __restrict__ out)
{
    const int tid  = threadIdx.x;
    const int lane = tid & 63;
    const int wid  = tid >> 6;
    const int wr   = wid >> 2;            // 0..1
    const int wc   = wid & 3;             // 0..3

    // XCD-partitioned mapping: each XCD owns 2 B-panels (W2 2MB, L2-fit);
    // local pairs share the A-panel.
    const int bid  = blockIdx.x;
    const int xcd  = bid & 7;
    const int loc  = bid >> 3;            // 0..127
    const int nbk  = (xcd << 1) | (loc & 1);   // 0..15
    const int mbk  = loc >> 1;                 // 0..63
    const int brow = mbk << 8, bcol = nbk << 8;

    const int l15  = lane & 15;
    const int mf0  = (brow >> 4) + (wr << 3);   // 8 A-fragments (rows)
    const int nf0  = (bcol >> 4) + (wc << 2);   // 4 B-fragments (cols)

    const unsigned short* a2p = A2 + (lane << 3);
    const unsigned short* w2p = W2 + (lane << 3);

    f32x4 acc[8][4];
#pragma unroll
    for (int i = 0; i < 8; ++i)
#pragma unroll
        for (int j = 0; j < 4; ++j) acc[i][j] = f32x4{0.f, 0.f, 0.f, 0.f};
    bf16x8 a[4][2], b[4][2];

    for (int t = 0; t < NT; ++t) {
        const int s2 = t << 1;

        // ---- B frags (8 coalesced loads, L2-resident)
#pragma unroll
        for (int n = 0; n < 4; ++n)
#pragma unroll
            for (int ks = 0; ks < 2; ++ks)
                b[n][ks] = *(const bf16x8*)(
                    w2p + (((size_t)(nf0 + n) * 64 + s2 + ks) << 9));

        // ---- A mh0 frags (8 coalesced loads, L3-resident)
#pragma unroll
        for (int m = 0; m < 4; ++m)
#pragma unroll
            for (int ks = 0; ks < 2; ++ks)
                a[m][ks] = *(const bf16x8*)(
                    a2p + (((size_t)(mf0 + m) * 64 + s2 + ks) << 9));

        // ---- MFMA mh0 (32)
#pragma unroll
        for (int ks = 0; ks < 2; ++ks)
#pragma unroll
            for (int m = 0; m < 4; ++m)
#pragma unroll
                for (int n = 0; n < 4; ++n)
                    acc[m][n] = __builtin_amdgcn_mfma_f32_16x16x32_bf16(
                        a[m][ks], b[n][ks], acc[m][n], 0, 0, 0);

        // ---- A mh1 frags (8 loads, reuse regs)
#pragma unroll
        for (int m = 0; m < 4; ++m)
#pragma unroll
            for (int ks = 0; ks < 2; ++ks)
                a[m][ks] = *(const bf16x8*)(
                    a2p + (((size_t)(mf0 + 4 + m) * 64 + s2 + ks) << 9));

        // ---- MFMA mh1 (32)
#pragma unroll
        for (int ks = 0; ks < 2; ++ks)
#pragma unroll
            for (int m = 0; m < 4; ++m)
#pragma unroll
                for (int n = 0; n < 4; ++n)
                    acc[4 + m][n] = __builtin_amdgcn_mfma_f32_16x16x32_bf16(
                        a[m][ks], b[n][ks], acc[4 + m][n], 0, 0, 0);
    }

    // ---- fused LSTM epilogue: n-index = gate for one h-col per lane
    const int hcol  = (((nbk << 2) + wc) << 4) + l15;
    const int crow0 = brow + (wr << 7) + ((lane >> 4) << 2);
    const int cb0   = bcol + (wc << 6) + l15;
    const float bs0 = bias[cb0];
    const float bs1 = bias[cb0 + 16];
    const float bs2 = bias[cb0 + 32];
    const float bs3 = bias[cb0 + 48];
    const size_t P  = (size_t)B_ * H_;
#pragma unroll
    for (int mf = 0; mf < 8; ++mf) {
#pragma unroll
        for (int j = 0; j < 4; ++j) {
            const int row = crow0 + mf * 16 + j;
            const size_t base = (size_t)row * H_ + hcol;
            float fg = sigf(acc[mf][0][j] + bs0);
            float ig = sigf(acc[mf][1][j] + bs1);
            float kg = tanhfast(acc[mf][2][j] + bs2);
            float og = sigf(acc[mf][3][j] + bs3);
            float cv = c[base];
            float cn = fg * cv + ig * kg;
            float hn = og * tanhfast(cn);
            out[base]         = og;
            out[P + base]     = cn;
            out[2 * P + base] = hn;
        }
    }
}

// ---------------------------------------------------------------- launch
extern "C" void kernel_launch(void* const* d_in, const int* in_sizes, int n_in,
                              void* d_out, int out_size, void* d_ws, size_t ws_size,
                              hipStream_t stream)
{
    const float* x  = (const float*)d_in[0];
    const float* c  = (const float*)d_in[1];
    const float* h  = (const float*)d_in[2];
    const float* Wx = (const float*)d_in[3];
    const float* bx = (const float*)d_in[4];
    const float* Wh = (const float*)d_in[5];
    const float* bh = (const float*)d_in[6];

    unsigned short* A2   = (unsigned short*)((char*)d_ws + OFF_A);
    unsigned short* W2   = (unsigned short*)((char*)d_ws + OFF_W);
    float*          bias = (float*)((char*)d_ws + OFF_BI);
    float*          out  = (float*)d_out;

    cvt_a2<<<16384, 256, 0, stream>>>(x, h, A2);
    cvt_w2<<<4096, 256, 0, stream>>>(Wx, Wh, W2);
    bias_kernel<<<16, 256, 0, stream>>>(bx, bh, bias);
    gemm_lstm<<<(M / 256) * (N / 256), 512, 0, stream>>>(
        A2, W2, bias, c, out);
}

// Round 17
// 350.611 us; speedup vs baseline: 1.2287x; 1.2287x over previous
//
#include <hip/hip_runtime.h>
#include <hip/hip_bf16.h>
#include <cstdint>

#define DI __device__ __forceinline__

typedef __attribute__((ext_vector_type(4)))  float f32x4;
typedef __attribute__((ext_vector_type(16))) float f32x16;
typedef __attribute__((ext_vector_type(8)))  short bf16x8;

static constexpr int B_ = 16384, I_ = 1024, H_ = 1024;
static constexpr int M = B_;          // 16384 rows
static constexpr int N = 4 * H_;      // 4096 gate-cols (stride-32 gate permutation)
static constexpr int K = I_ + H_;     // 2048 ([x | h])
static constexpr int NT = K / 64;     // 32 K-tiles

// workspace layout (bytes)
static constexpr size_t OFF_A  = 0;                         // M*K bf16   (64 MB)
static constexpr size_t OFF_W  = OFF_A + (size_t)M * K * 2; // N*K bf16   (16 MB)
static constexpr size_t OFF_BI = OFF_W + (size_t)N * K * 2; // N f32      (16 KB)

DI unsigned short f2bf(float f) {
    union { float f; unsigned u; } v; v.f = f;
    unsigned r = v.u + 0x7FFFu + ((v.u >> 16) & 1u);
    return (unsigned short)(r >> 16);
}

// ---------------------------------------------------------------- convert
// A' = [x | h] (M x K) bf16 row-major. W' rows permuted for the 32-wide
// MFMA tiles: GEMM col c -> gate = (c>>5)&3, hcol = (c>>7)*32 + (c&31).
// Each lane's 4 consecutive 32-col n-tiles then hold the 4 gates of ONE hcol.
__global__ void cvt_kernel(const float* __restrict__ x, const float* __restrict__ h,
                           const float* __restrict__ Wx, const float* __restrict__ Wh,
                           unsigned short* __restrict__ A, unsigned short* __restrict__ W)
{
    long tid = (long)blockIdx.x * blockDim.x + threadIdx.x;
    long row = tid >> 9;
    int  col = (int)(tid & 511) * 4;
    const float* src;
    unsigned short* dst;
    if (row < M) {
        src = (col < I_) ? x + (size_t)row * I_ + col
                         : h + (size_t)row * H_ + (col - I_);
        dst = A + (size_t)row * K + col;
    } else {
        int r = (int)(row - M);                 // dst row in W' = GEMM col
        int gate = (r >> 5) & 3;
        int hcol = ((r >> 7) << 5) | (r & 31);
        int srow = gate * H_ + hcol;            // src row in [4,H] stack
        src = (col < I_) ? Wx + (size_t)srow * I_ + col
                         : Wh + (size_t)srow * H_ + (col - I_);
        dst = W + (size_t)r * K + col;
    }
    float4 v = *(const float4*)src;
    ushort4 o;
    o.x = f2bf(v.x); o.y = f2bf(v.y); o.z = f2bf(v.z); o.w = f2bf(v.w);
    *(ushort4*)dst = o;
}

__global__ void bias_kernel(const float* __restrict__ bx, const float* __restrict__ bh,
                            float* __restrict__ bias)
{
    int r = blockIdx.x * blockDim.x + threadIdx.x;
    if (r < N) {
        int gate = (r >> 5) & 3;
        int hcol = ((r >> 7) << 5) | (r & 31);
        int s = gate * H_ + hcol;
        bias[r] = bx[s] + bh[s];
    }
}

// ---------------------------------------------------------------- GEMM 256x256
// r10 base (best measured: one vmcnt(0)+barrier per K-tile, swizzled LDS,
// XCD-partitioned mapping) with the MFMA shape switched to 32x32x16:
// +20% matrix-pipe FLOP/cy (2495 vs 2075 TF ubench) and half the MFMA
// instruction count. 8 waves = 4 wr (64-row) x 2 wc (128-col); per wave
// 2x4 accs of f32x16. A/B operand layout: row|col = lane&31,
// k = (lane>>5)*8 + j -> same ds_read_b128 XOR-swizzle stays conflict-free
// (<=2 lanes/slot within each 16-lane phase).
DI void stage_half(const unsigned short* __restrict__ g, int grow0, int kcol,
                   unsigned short* ldsbase, int tid)
{
    const int w    = tid >> 6, lane = tid & 63;
    const int rsub = (w << 3) + (lane >> 3);
    const int kk   = kcol + (((lane & 7) ^ (lane >> 3)) << 3);  // inverse-swizzled src
#pragma unroll
    for (int l = 0; l < 2; ++l) {
        const unsigned short* gp = g + (size_t)(grow0 + (l << 6) + rsub) * K + kk;
        unsigned short* lp = ldsbase + (((l << 6) + (w << 3)) << 6);
        __builtin_amdgcn_global_load_lds(
            (const __attribute__((address_space(1))) void*)gp,
            (__attribute__((address_space(3))) void*)lp, 16, 0, 0);
    }
}

// 32x32x16 fragment read: row' = row (lane&31 within tile), 16B slot =
// (s16*2 + (lane>>5)) ^ (row&7)
DI bf16x8 ldfrag32(const unsigned short* tile, int row, int s16, int lane)
{
    const int sl = (((s16 << 1) + (lane >> 5)) ^ (row & 7));
    return *(const bf16x8*)(tile + (row << 6) + (sl << 3));
}

DI float sigf(float v) { return 1.f / (1.f + __expf(-v)); }
DI float tanhfast(float v) {
    float vc = fminf(fmaxf(v, -15.f), 15.f);
    float e  = __expf(2.f * vc);
    return (e - 1.f) / (e + 1.f);
}

__global__ __launch_bounds__(512, 2) void gemm_lstm(
    const unsigned short* __restrict__ Abf, const unsigned short* __restrict__ Wbf,
    const float* __restrict__ bias, const float* __restrict__ c,
    float* __restrict__ out)
{
    __shared__ __align__(16) unsigned short sh[65536];   // 128 KiB

    const int tid  = threadIdx.x;
    const int lane = tid & 63;
    const int wid  = tid >> 6;
    const int wr   = wid >> 1;            // 0..3  (64-row slice)
    const int wc   = wid & 1;             // 0..1  (128-col slice)

    // XCD-partitioned mapping (r10): each XCD owns 2 B-panels
    const int bid  = blockIdx.x;
    const int xcd  = bid & 7;
    const int loc  = bid >> 3;            // 0..127
    const int nbk  = (xcd << 1) | (loc & 1);   // 0..15
    const int mbk  = loc >> 1;                 // 0..63
    const int brow = mbk << 8, bcol = nbk << 8;

    const int l31  = lane & 31;
    const int rA0  = (wr << 6) + l31;     // + mt*32
    const int rB0  = (wc << 7) + l31;     // + nt*32

    f32x16 acc[2][4];
#pragma unroll
    for (int i = 0; i < 2; ++i)
#pragma unroll
        for (int j = 0; j < 4; ++j)
#pragma unroll
            for (int e = 0; e < 16; ++e) acc[i][j][e] = 0.f;
    bf16x8 a[4], b[4][4];

    // prologue: stage tile0, drain, publish
    {
        stage_half(Abf, brow,       0, sh,         tid);
        stage_half(Abf, brow + 128, 0, sh + 8192,  tid);
        stage_half(Wbf, bcol,       0, sh + 16384, tid);
        stage_half(Wbf, bcol + 128, 0, sh + 24576, tid);
        asm volatile("s_waitcnt vmcnt(0)" ::: "memory");
        __builtin_amdgcn_s_barrier();
    }

    for (int t = 0; t < NT; ++t) {
        const int q = t & 1;
        unsigned short* curA = sh + q * 32768;
        unsigned short* curB = curA + 16384;
        unsigned short* nxtA = sh + (q ^ 1) * 32768;
        unsigned short* nxtB = nxtA + 16384;
        const int k1 = ((t + 1) & 31) << 6;   // wrapped tail: garbage into dead buf

        // stage entire tile t+1 (nxt freed at the (t-1)-end barrier)
        stage_half(Abf, brow,       k1, nxtA,        tid);
        stage_half(Abf, brow + 128, k1, nxtA + 8192, tid);
        stage_half(Wbf, bcol,       k1, nxtB,        tid);
        stage_half(Wbf, bcol + 128, k1, nxtB + 8192, tid);

        // ---- B frags (16 reads) ----
#pragma unroll
        for (int nt = 0; nt < 4; ++nt)
#pragma unroll
            for (int s = 0; s < 4; ++s)
                b[nt][s] = ldfrag32(curB, rB0 + nt * 32, s, lane);

        // ---- A mt0 (4 reads) + MFMA (16 of 32x32x16) ----
#pragma unroll
        for (int s = 0; s < 4; ++s) a[s] = ldfrag32(curA, rA0, s, lane);
#pragma unroll
        for (int s = 0; s < 4; ++s)
#pragma unroll
            for (int nt = 0; nt < 4; ++nt)
                acc[0][nt] = __builtin_amdgcn_mfma_f32_32x32x16_bf16(
                    a[s], b[nt][s], acc[0][nt], 0, 0, 0);

        // ---- A mt1 (4 reads, reuse regs) + MFMA ----
#pragma unroll
        for (int s = 0; s < 4; ++s) a[s] = ldfrag32(curA, rA0 + 32, s, lane);
#pragma unroll
        for (int s = 0; s < 4; ++s)
#pragma unroll
            for (int nt = 0; nt < 4; ++nt)
                acc[1][nt] = __builtin_amdgcn_mfma_f32_32x32x16_bf16(
                    a[s], b[nt][s], acc[1][nt], 0, 0, 0);

        // tile-end: publish tile t+1 and release cur
        asm volatile("s_waitcnt vmcnt(0)" ::: "memory");
        __builtin_amdgcn_s_barrier();
    }

    // ---- fused LSTM epilogue ----
    // C/D 32x32 map: col = lane&31, row = (reg&3) + 8*(reg>>2) + 4*(lane>>5).
    // nt = gate (stride-32 permutation); hcol = ((bcol + wc*128)>>7)*32 + l31.
    const int c0    = bcol + (wc << 7);
    const int hcol  = ((c0 >> 7) << 5) + l31;
    const float bs0 = bias[c0 +       l31];
    const float bs1 = bias[c0 +  32 + l31];
    const float bs2 = bias[c0 +  64 + l31];
    const float bs3 = bias[c0 +  96 + l31];
    const int rbase = brow + (wr << 6) + ((lane >> 5) << 2);
    const size_t P  = (size_t)B_ * H_;
#pragma unroll
    for (int mt = 0; mt < 2; ++mt) {
#pragma unroll
        for (int r = 0; r < 16; ++r) {
            const int row = rbase + mt * 32 + (r & 3) + ((r >> 2) << 3);
            const size_t base = (size_t)row * H_ + hcol;
            float fg = sigf(acc[mt][0][r] + bs0);
            float ig = sigf(acc[mt][1][r] + bs1);
            float kg = tanhfast(acc[mt][2][r] + bs2);
            float og = sigf(acc[mt][3][r] + bs3);
            float cv = c[base];
            float cn = fg * cv + ig * kg;
            float hn = og * tanhfast(cn);
            out[base]         = og;
            out[P + base]     = cn;
            out[2 * P + base] = hn;
        }
    }
}

// ---------------------------------------------------------------- launch
extern "C" void kernel_launch(void* const* d_in, const int* in_sizes, int n_in,
                              void* d_out, int out_size, void* d_ws, size_t ws_size,
                              hipStream_t stream)
{
    const float* x  = (const float*)d_in[0];
    const float* c  = (const float*)d_in[1];
    const float* h  = (const float*)d_in[2];
    const float* Wx = (const float*)d_in[3];
    const float* bx = (const float*)d_in[4];
    const float* Wh = (const float*)d_in[5];
    const float* bh = (const float*)d_in[6];

    unsigned short* Abf  = (unsigned short*)((char*)d_ws + OFF_A);
    unsigned short* Wbf  = (unsigned short*)((char*)d_ws + OFF_W);
    float*          bias = (float*)((char*)d_ws + OFF_BI);
    float*          out  = (float*)d_out;

    cvt_kernel<<<40960, 256, 0, stream>>>(x, h, Wx, Wh, Abf, Wbf);
    bias_kernel<<<16, 256, 0, stream>>>(bx, bh, bias);
    gemm_lstm<<<(M / 256) * (N / 256), 512, 0, stream>>>(
        Abf, Wbf, bias, c, out);
}